// Round 1
// baseline (666.182 us; speedup 1.0000x reference)
//
#include <hip/hip_runtime.h>
#include <cstdint>
#include <cstddef>

// Problem constants (from reference)
#define OUT_F 4096
#define IN_F  11008
#define VECD  8
#define NVEC  (OUT_F * IN_F / VECD)   // 5,636,096 vectors
#define VPR   (IN_F / VECD)           // 1376 vectors per output row
#define M_DIM 4096                    // 2*2048 flattened batch*seq
#define N_DIM OUT_F
#define K_DIM IN_F

typedef __attribute__((ext_vector_type(4))) float f32x4;
typedef __attribute__((ext_vector_type(8))) __bf16 bf16x8;
typedef __attribute__((ext_vector_type(4))) unsigned int u32x4;

__device__ inline unsigned short f2bf(float f) {     // RNE
  union { float f; unsigned int u; } v; v.f = f;
  unsigned int u = v.u;
  unsigned int r = u + 0x7FFFu + ((u >> 16) & 1u);
  return (unsigned short)(r >> 16);
}

// ---------------------------------------------------------------------------
// Phase 1: dequant W + cast X -> bf16.  UNCHANGED this round (isolating the
// GEMM schedule change).  ~258-280 µs measured; runs at only ~1.4 TB/s vs a
// ~61 µs / 6.3 TB/s roofline (383 MB of traffic) — it is the next target once
// it shows up in the top-5 counters (it will, once gemm drops below it).
// ---------------------------------------------------------------------------
__global__ __launch_bounds__(256) void dequant_cast_kernel(
    const float* __restrict__ x, const int* __restrict__ indices,
    const float* __restrict__ cb, const float* __restrict__ scales,
    unsigned short* __restrict__ xb, unsigned short* __restrict__ wb) {
  int v = blockIdx.x * 256 + threadIdx.x;
  if (v >= NVEC) return;

  int id = indices[v];
  int o  = v / VPR;
  float s = scales[o];

  const f32x4* c = (const f32x4*)(cb + (size_t)id * VECD);
  f32x4 c0 = c[0], c1 = c[1];
  u32x4 w;
  w.x = (unsigned)f2bf(c0.x * s) | ((unsigned)f2bf(c0.y * s) << 16);
  w.y = (unsigned)f2bf(c0.z * s) | ((unsigned)f2bf(c0.w * s) << 16);
  w.z = (unsigned)f2bf(c1.x * s) | ((unsigned)f2bf(c1.y * s) << 16);
  w.w = (unsigned)f2bf(c1.z * s) | ((unsigned)f2bf(c1.w * s) << 16);
  *(u32x4*)(wb + (size_t)v * 8) = w;

  const f32x4* xp = (const f32x4*)(x + (size_t)v * 8);
  f32x4 x0 = xp[0], x1 = xp[1];
  u32x4 q;
  q.x = (unsigned)f2bf(x0.x) | ((unsigned)f2bf(x0.y) << 16);
  q.y = (unsigned)f2bf(x0.z) | ((unsigned)f2bf(x0.w) << 16);
  q.z = (unsigned)f2bf(x1.x) | ((unsigned)f2bf(x1.y) << 16);
  q.w = (unsigned)f2bf(x1.z) | ((unsigned)f2bf(x1.w) << 16);
  *(u32x4*)(xb + (size_t)v * 8) = q;
}

// ---------------------------------------------------------------------------
// Phase 2: C[M,N] = A[M,K] * B[N,K]^T (bf16, K-contiguous; fp32 out)
//
// 256x256 tile, 512 threads (8 waves, wave-tile 128x64, acc[8][4]).
// Round-5 change: m201-style PHASE SPLIT.  Previous structure (one barrier +
// 12 ds_reads + 32 MFMA per K-step) sat at MfmaUtil 47% — the "2ph" regime
// where setprio/swizzle are null and stage->read->compute serializes.  Now
// each K-step is 2 phases of 16 MFMA (m201's exact granularity):
//   ph0: ds af[0..3]+bfr[0..3] | stage-A(t+2) | bar | lgkmcnt(0) |
//        prio1 16xMFMA prio0 | bar
//   ph1: ds af[4..7]          | stage-B(t+2) | bar | lgkmcnt(0) |
//        prio1 16xMFMA prio0 | vmcnt(4) | bar
// Counted-vmcnt semantics preserved from the verified kernel: 4 GLD16/tile
// issued A-then-B, so at the tile-end vmcnt(4) the oldest 4 (= tile t+1's
// data, needed next) are drained while tile t+2's 4 stay in flight.
// Buffer-overwrite safety unchanged: buf (t+2)%3 was last ds_read at tile
// t-1; every phase does lgkmcnt(0) before its trailing barrier, so those
// reads are complete for ALL waves before tile t begins staging into it.
// Tail iters issue clamped redundant fetches (uniform outstanding count).
// XOR bank swizzle retained (zero conflicts, counter-verified).
// ---------------------------------------------------------------------------
#define GLD16(g, l)                                                     \
  __builtin_amdgcn_global_load_lds(                                     \
      (const __attribute__((address_space(1))) void*)(g),               \
      (__attribute__((address_space(3))) void*)(l), 16, 0, 0)

__global__ __launch_bounds__(512, 2) void gemm_bt_kernel(
    const unsigned short* __restrict__ A,   // M x K bf16 (X)
    const unsigned short* __restrict__ B,   // N x K bf16 (W)
    float* __restrict__ C) {                // M x N fp32
  extern __shared__ unsigned short SMEM[];  // 3*(8192+8192) = 96 KB
  unsigned short* SA = SMEM;                // [3][8192]
  unsigned short* SB = SMEM + 3 * 8192;     // [3][8192]

  const int tid  = threadIdx.x;
  const int bm   = blockIdx.x >> 4;         // 0..15
  const int bn   = blockIdx.x & 15;         // 0..15
  const int lane = tid & 63;
  const int wave = tid >> 6;                // 0..7
  const int wm   = (wave & 1) * 128;        // 2 waves in M
  const int wn   = (wave >> 1) * 64;        // 4 waves in N
  const int lrow = lane & 15;
  const int kgrp = lane >> 4;
  const int kslot = (kgrp ^ ((lrow >> 1) & 3)) * 8;

  // Staging: 512 threads, 4 GLD16 each = 32 KB/iter. Thread t owns LDS slot
  // (row = t>>2 [+128], chunk cs = t&3); fetches global chunk cs^((row>>1)&3)
  // (same XOR term for row+128 since 128/2 ≡ 0 mod 4).
  const int srow = tid >> 2;                // 0..127
  const int cg   = (tid & 3) ^ ((srow >> 1) & 3);
  const unsigned short* a0 = A + (size_t)(bm * 256 + srow) * K_DIM + cg * 8;
  const unsigned short* a1 = a0 + (size_t)128 * K_DIM;
  const unsigned short* b0 = B + (size_t)(bn * 256 + srow) * K_DIM + cg * 8;
  const unsigned short* b1 = b0 + (size_t)128 * K_DIM;
  const int l0 = tid * 8;                   // rows 0..127 region
  const int l1 = 4096 + tid * 8;            // rows 128..255 region

#define STAGE_A(pbuf, kf)                                 \
  do {                                                    \
    GLD16(a0 + (kf), &SA[(pbuf) * 8192 + l0]);            \
    GLD16(a1 + (kf), &SA[(pbuf) * 8192 + l1]);            \
  } while (0)
#define STAGE_B(pbuf, kf)                                 \
  do {                                                    \
    GLD16(b0 + (kf), &SB[(pbuf) * 8192 + l0]);            \
    GLD16(b1 + (kf), &SB[(pbuf) * 8192 + l1]);            \
  } while (0)

  f32x4 acc[8][4];
#pragma unroll
  for (int i = 0; i < 8; i++)
#pragma unroll
    for (int j = 0; j < 4; j++) acc[i][j] = f32x4{0.f, 0.f, 0.f, 0.f};

  // Prologue: tiles 0 and 1; issue order A,B per tile so oldest-4 = one tile.
  STAGE_A(0, 0);
  STAGE_B(0, 0);
  STAGE_A(1, 32);
  STAGE_B(1, 32);
  asm volatile("s_waitcnt vmcnt(4)\n\ts_barrier" ::: "memory");  // tile 0 in
  int cbuf = 0, pbuf = 2;

  for (int k0 = 0; k0 < K_DIM; k0 += 32) {
    int kf = k0 + 64;                       // prefetch tile k+2 (clamped tail)
    if (kf > K_DIM - 32) kf = K_DIM - 32;

    bf16x8 af[8], bfr[4];

    // ---------------- phase 0: m-frags 0..3 ----------------
#pragma unroll
    for (int i = 0; i < 4; i++)
      af[i] = *(const bf16x8*)&SA[cbuf * 8192 + (wm + i * 16 + lrow) * 32 + kslot];
#pragma unroll
    for (int j = 0; j < 4; j++)
      bfr[j] = *(const bf16x8*)&SB[cbuf * 8192 + (wn + j * 16 + lrow) * 32 + kslot];
    STAGE_A(pbuf, kf);

    __builtin_amdgcn_s_barrier();
    asm volatile("s_waitcnt lgkmcnt(0)" ::: "memory");
    __builtin_amdgcn_s_setprio(1);
#pragma unroll
    for (int i = 0; i < 4; i++)
#pragma unroll
      for (int j = 0; j < 4; j++)
        acc[i][j] = __builtin_amdgcn_mfma_f32_16x16x32_bf16(
            af[i], bfr[j], acc[i][j], 0, 0, 0);
    __builtin_amdgcn_s_setprio(0);
    __builtin_amdgcn_s_barrier();

    // ---------------- phase 1: m-frags 4..7 ----------------
#pragma unroll
    for (int i = 4; i < 8; i++)
      af[i] = *(const bf16x8*)&SA[cbuf * 8192 + (wm + i * 16 + lrow) * 32 + kslot];
    STAGE_B(pbuf, kf);

    __builtin_amdgcn_s_barrier();
    asm volatile("s_waitcnt lgkmcnt(0)" ::: "memory");
    __builtin_amdgcn_s_setprio(1);
#pragma unroll
    for (int i = 4; i < 8; i++)
#pragma unroll
      for (int j = 0; j < 4; j++)
        acc[i][j] = __builtin_amdgcn_mfma_f32_16x16x32_bf16(
            af[i], bfr[j], acc[i][j], 0, 0, 0);
    __builtin_amdgcn_s_setprio(0);
    // Drain oldest 4 (tile t+1, needed next iter); keep tile t+2's 4 flying.
    asm volatile("s_waitcnt vmcnt(4)\n\ts_barrier" ::: "memory");

    cbuf = (cbuf == 2) ? 0 : cbuf + 1;
    pbuf = (pbuf == 2) ? 0 : pbuf + 1;
  }
#undef STAGE_A
#undef STAGE_B

  // Epilogue: C/D layout col = lane&15, row = (lane>>4)*4 + reg  [m89-verified]
#pragma unroll
  for (int i = 0; i < 8; i++) {
    const int row0 = bm * 256 + wm + i * 16 + kgrp * 4;
#pragma unroll
    for (int j = 0; j < 4; j++) {
      const int col = bn * 256 + wn + j * 16 + lrow;
#pragma unroll
      for (int r = 0; r < 4; r++)
        C[(size_t)(row0 + r) * N_DIM + col] = acc[i][j][r];
    }
  }
}

// ---------------------------------------------------------------------------
// Fallback (only if workspace is too small for the bf16 operands).
// ---------------------------------------------------------------------------
__global__ __launch_bounds__(256) void naive_kernel(
    const float* __restrict__ x, const int* __restrict__ indices,
    const float* __restrict__ cb, const float* __restrict__ scales,
    float* __restrict__ out) {
  int n = blockIdx.x * 256 + threadIdx.x;
  int m = blockIdx.y;
  if (n >= N_DIM) return;
  float s = scales[n];
  const float* xr = x + (size_t)m * IN_F;
  const int* ir = indices + (size_t)n * VPR;
  float acc = 0.f;
  for (int v = 0; v < VPR; v++) {
    int id = ir[v];
    const float* c = cb + (size_t)id * 8;
#pragma unroll
    for (int e = 0; e < 8; e++) acc += xr[v * 8 + e] * c[e];
  }
  out[(size_t)m * N_DIM + n] = acc * s;
}

extern "C" void kernel_launch(void* const* d_in, const int* in_sizes, int n_in,
                              void* d_out, int out_size, void* d_ws, size_t ws_size,
                              hipStream_t stream) {
  const float* x       = (const float*)d_in[0];   // (2,2048,11008) fp32
  const int*   indices = (const int*)d_in[1];     // (5636096,) int32
  const float* cb      = (const float*)d_in[2];   // (32768,8) fp32
  const float* scales  = (const float*)d_in[3];   // (4096,1) fp32
  float* out = (float*)d_out;                     // (2,2048,4096) fp32

  const size_t xb_elems = (size_t)M_DIM * K_DIM;  // 45,088,768
  const size_t wb_elems = (size_t)N_DIM * K_DIM;  // 45,088,768
  const size_t need = (xb_elems + wb_elems) * sizeof(unsigned short); // ~172 MB

  if (ws_size >= need) {
    unsigned short* xb = (unsigned short*)d_ws;
    unsigned short* wb = xb + xb_elems;
    dequant_cast_kernel<<<NVEC / 256, 256, 0, stream>>>(x, indices, cb, scales,
                                                        xb, wb);
    gemm_bt_kernel<<<(M_DIM / 256) * (N_DIM / 256), 512, 6 * 8192 * 2, stream>>>(
        xb, wb, out);
  } else {
    naive_kernel<<<dim3(N_DIM / 256, M_DIM), 256, 0, stream>>>(x, indices, cb,
                                                               scales, out);
  }
}

// Round 2
// 650.622 us; speedup vs baseline: 1.0239x; 1.0239x over previous
//
#include <hip/hip_runtime.h>
#include <cstdint>
#include <cstddef>

// Problem constants (from reference)
#define OUT_F 4096
#define IN_F  11008
#define VECD  8
#define NVEC  (OUT_F * IN_F / VECD)   // 5,636,096 vectors
#define VPR   (IN_F / VECD)           // 1376 vectors per output row
#define M_DIM 4096                    // 2*2048 flattened batch*seq
#define N_DIM OUT_F
#define K_DIM IN_F

typedef __attribute__((ext_vector_type(4))) float f32x4;
typedef __attribute__((ext_vector_type(8))) __bf16 bf16x8;
typedef __attribute__((ext_vector_type(4))) unsigned int u32x4;

__device__ inline unsigned short f2bf(float f) {     // RNE
  union { float f; unsigned int u; } v; v.f = f;
  unsigned int u = v.u;
  unsigned int r = u + 0x7FFFu + ((u >> 16) & 1u);
  return (unsigned short)(r >> 16);
}

// ---------------------------------------------------------------------------
// Phase 1: dequant W + cast X -> bf16.
// Round-6 change: 4 vectors per thread at coalesced stride Q=NVEC/4.
// Theory: the ~280 µs (vs 61 µs roofline on 384 MB) is gather request-rate /
// latency bound — each thread had ONE dependent index->2x16B-gather chain and
// the random 32B gathers hit ~64 distinct L2 lines per wave instruction.
// Batching 4 independent chains per thread (4 idx loads, then 8 gathers, then
// 8 x-loads issued back-to-back) gives 4x the memory-level parallelism at
// identical coalescing (lane strides unchanged: 4B idx / 32B x / 16B stores).
// VALU work unchanged (~6 µs chip-wide, not the limit). Numerics identical.
// ---------------------------------------------------------------------------
__global__ __launch_bounds__(256) void dequant_cast_kernel(
    const float* __restrict__ x, const int* __restrict__ indices,
    const float* __restrict__ cb, const float* __restrict__ scales,
    unsigned short* __restrict__ xb, unsigned short* __restrict__ wb) {
  const int Q = NVEC / 4;                   // 1,409,024 (divisible by 256)
  int t = blockIdx.x * 256 + threadIdx.x;
  if (t >= Q) return;

  int v[4], id[4];
  float s[4];
#pragma unroll
  for (int k = 0; k < 4; k++) v[k] = t + k * Q;
#pragma unroll
  for (int k = 0; k < 4; k++) id[k] = indices[v[k]];   // 4 coalesced loads
#pragma unroll
  for (int k = 0; k < 4; k++) s[k] = scales[v[k] / VPR];  // wave-broadcast

  // 8 independent random gathers in flight (each 16B; c[k][0]/c[k][1] share a
  // 64B line since codebook vectors are 32B-aligned 32B chunks).
  f32x4 c[4][2];
#pragma unroll
  for (int k = 0; k < 4; k++) {
    const f32x4* cp = (const f32x4*)(cb + (size_t)id[k] * VECD);
    c[k][0] = cp[0];
    c[k][1] = cp[1];
  }

  // 8 coalesced x loads (lane stride 32B within each instruction).
  f32x4 xv[4][2];
#pragma unroll
  for (int k = 0; k < 4; k++) {
    const f32x4* xp = (const f32x4*)(x + (size_t)v[k] * 8);
    xv[k][0] = xp[0];
    xv[k][1] = xp[1];
  }

#pragma unroll
  for (int k = 0; k < 4; k++) {
    u32x4 w;
    w.x = (unsigned)f2bf(c[k][0].x * s[k]) | ((unsigned)f2bf(c[k][0].y * s[k]) << 16);
    w.y = (unsigned)f2bf(c[k][0].z * s[k]) | ((unsigned)f2bf(c[k][0].w * s[k]) << 16);
    w.z = (unsigned)f2bf(c[k][1].x * s[k]) | ((unsigned)f2bf(c[k][1].y * s[k]) << 16);
    w.w = (unsigned)f2bf(c[k][1].z * s[k]) | ((unsigned)f2bf(c[k][1].w * s[k]) << 16);
    *(u32x4*)(wb + (size_t)v[k] * 8) = w;

    u32x4 q;
    q.x = (unsigned)f2bf(xv[k][0].x) | ((unsigned)f2bf(xv[k][0].y) << 16);
    q.y = (unsigned)f2bf(xv[k][0].z) | ((unsigned)f2bf(xv[k][0].w) << 16);
    q.z = (unsigned)f2bf(xv[k][1].x) | ((unsigned)f2bf(xv[k][1].y) << 16);
    q.w = (unsigned)f2bf(xv[k][1].z) | ((unsigned)f2bf(xv[k][1].w) << 16);
    *(u32x4*)(xb + (size_t)v[k] * 8) = q;
  }
}

// ---------------------------------------------------------------------------
// Phase 2: C[M,N] = A[M,K] * B[N,K]^T (bf16, K-contiguous; fp32 out)
//
// EXACT round-0 kernel (measured 355.9 µs, MfmaUtil 47.3%, 0 bank conflicts).
// Round-5's m201-style 2-phase graft REGRESSED (373 µs, MfmaUtil 41%): the
// extra 3 barriers/K-step + lgkmcnt(0)-before-all-MFMA removed the compiler's
// fine-grained per-operand lgkmcnt scheduling. The counted vmcnt(4) (the real
// T4 ingredient) was already here. Do not re-graft phases without the full
// m201 BK=64/derived-waits port.
//
// 256x256 tile, 512 threads (8 waves, wave-tile 128x64, acc[8][4]).
// 3 LDS buffers, raw `s_waitcnt vmcnt(4); s_barrier` per iter (keeps the
// 4 newest global_load_lds in flight across the barrier, AITER-style).
// Safety: buffer (k+2)%3 was last read at iter k-1, whose ds_reads complete
// before barrier k; tail iters issue clamped redundant fetches so the
// outstanding-load count stays uniform (vmcnt(4) always correct).
// XOR bank swizzle retained (zero conflicts, verified).
// ---------------------------------------------------------------------------
#define GLD16(g, l)                                                     \
  __builtin_amdgcn_global_load_lds(                                     \
      (const __attribute__((address_space(1))) void*)(g),               \
      (__attribute__((address_space(3))) void*)(l), 16, 0, 0)

__global__ __launch_bounds__(512, 2) void gemm_bt_kernel(
    const unsigned short* __restrict__ A,   // M x K bf16 (X)
    const unsigned short* __restrict__ B,   // N x K bf16 (W)
    float* __restrict__ C) {                // M x N fp32
  extern __shared__ unsigned short SMEM[];  // 3*(8192+8192) = 96 KB
  unsigned short* SA = SMEM;                // [3][8192]
  unsigned short* SB = SMEM + 3 * 8192;     // [3][8192]

  const int tid  = threadIdx.x;
  const int bm   = blockIdx.x >> 4;         // 0..15
  const int bn   = blockIdx.x & 15;         // 0..15
  const int lane = tid & 63;
  const int wave = tid >> 6;                // 0..7
  const int wm   = (wave & 1) * 128;        // 2 waves in M
  const int wn   = (wave >> 1) * 64;        // 4 waves in N
  const int lrow = lane & 15;
  const int kgrp = lane >> 4;
  const int kslot = (kgrp ^ ((lrow >> 1) & 3)) * 8;

  // Staging: 512 threads, 4 GLD16 each = 32 KB/iter. Thread t owns LDS slot
  // (row = t>>2 [+128], chunk cs = t&3); fetches global chunk cs^((row>>1)&3)
  // (same XOR term for row+128 since 128/2 ≡ 0 mod 4).
  const int srow = tid >> 2;                // 0..127
  const int cg   = (tid & 3) ^ ((srow >> 1) & 3);
  const unsigned short* a0 = A + (size_t)(bm * 256 + srow) * K_DIM + cg * 8;
  const unsigned short* a1 = a0 + (size_t)128 * K_DIM;
  const unsigned short* b0 = B + (size_t)(bn * 256 + srow) * K_DIM + cg * 8;
  const unsigned short* b1 = b0 + (size_t)128 * K_DIM;
  const int l0 = tid * 8;                   // rows 0..127 region
  const int l1 = 4096 + tid * 8;            // rows 128..255 region

#define STAGE(pbuf, kf)                                   \
  do {                                                    \
    GLD16(a0 + (kf), &SA[(pbuf) * 8192 + l0]);            \
    GLD16(a1 + (kf), &SA[(pbuf) * 8192 + l1]);            \
    GLD16(b0 + (kf), &SB[(pbuf) * 8192 + l0]);            \
    GLD16(b1 + (kf), &SB[(pbuf) * 8192 + l1]);            \
  } while (0)

  f32x4 acc[8][4];
#pragma unroll
  for (int i = 0; i < 8; i++)
#pragma unroll
    for (int j = 0; j < 4; j++) acc[i][j] = f32x4{0.f, 0.f, 0.f, 0.f};

  STAGE(0, 0);                              // tile 0 -> buf 0
  STAGE(1, 32);                             // tile 1 -> buf 1
  int cbuf = 0, pbuf = 2;

  for (int k0 = 0; k0 < K_DIM; k0 += 32) {
    // Wait for the OLDEST 4 loads (this iter's tile); keep newest 4 flying.
    asm volatile("s_waitcnt vmcnt(4)\n\ts_barrier" ::: "memory");

    int kf = k0 + 64;                       // prefetch tile k+2 (clamped tail)
    if (kf > K_DIM - 32) kf = K_DIM - 32;
    STAGE(pbuf, kf);

    bf16x8 af[8], bfr[4];
#pragma unroll
    for (int i = 0; i < 8; i++)
      af[i] = *(const bf16x8*)&SA[cbuf * 8192 + (wm + i * 16 + lrow) * 32 + kslot];
#pragma unroll
    for (int j = 0; j < 4; j++)
      bfr[j] = *(const bf16x8*)&SB[cbuf * 8192 + (wn + j * 16 + lrow) * 32 + kslot];

#pragma unroll
    for (int i = 0; i < 8; i++)
#pragma unroll
      for (int j = 0; j < 4; j++)
        acc[i][j] = __builtin_amdgcn_mfma_f32_16x16x32_bf16(
            af[i], bfr[j], acc[i][j], 0, 0, 0);

    cbuf = (cbuf == 2) ? 0 : cbuf + 1;
    pbuf = (pbuf == 2) ? 0 : pbuf + 1;
  }
#undef STAGE

  // Epilogue: C/D layout col = lane&15, row = (lane>>4)*4 + reg  [m89-verified]
#pragma unroll
  for (int i = 0; i < 8; i++) {
    const int row0 = bm * 256 + wm + i * 16 + kgrp * 4;
#pragma unroll
    for (int j = 0; j < 4; j++) {
      const int col = bn * 256 + wn + j * 16 + lrow;
#pragma unroll
      for (int r = 0; r < 4; r++)
        C[(size_t)(row0 + r) * N_DIM + col] = acc[i][j][r];
    }
  }
}

// ---------------------------------------------------------------------------
// Fallback (only if workspace is too small for the bf16 operands).
// ---------------------------------------------------------------------------
__global__ __launch_bounds__(256) void naive_kernel(
    const float* __restrict__ x, const int* __restrict__ indices,
    const float* __restrict__ cb, const float* __restrict__ scales,
    float* __restrict__ out) {
  int n = blockIdx.x * 256 + threadIdx.x;
  int m = blockIdx.y;
  if (n >= N_DIM) return;
  float s = scales[n];
  const float* xr = x + (size_t)m * IN_F;
  const int* ir = indices + (size_t)n * VPR;
  float acc = 0.f;
  for (int v = 0; v < VPR; v++) {
    int id = ir[v];
    const float* c = cb + (size_t)id * 8;
#pragma unroll
    for (int e = 0; e < 8; e++) acc += xr[v * 8 + e] * c[e];
  }
  out[(size_t)m * N_DIM + n] = acc * s;
}

extern "C" void kernel_launch(void* const* d_in, const int* in_sizes, int n_in,
                              void* d_out, int out_size, void* d_ws, size_t ws_size,
                              hipStream_t stream) {
  const float* x       = (const float*)d_in[0];   // (2,2048,11008) fp32
  const int*   indices = (const int*)d_in[1];     // (5636096,) int32
  const float* cb      = (const float*)d_in[2];   // (32768,8) fp32
  const float* scales  = (const float*)d_in[3];   // (4096,1) fp32
  float* out = (float*)d_out;                     // (2,2048,4096) fp32

  const size_t xb_elems = (size_t)M_DIM * K_DIM;  // 45,088,768
  const size_t wb_elems = (size_t)N_DIM * K_DIM;  // 45,088,768
  const size_t need = (xb_elems + wb_elems) * sizeof(unsigned short); // ~172 MB

  if (ws_size >= need) {
    unsigned short* xb = (unsigned short*)d_ws;
    unsigned short* wb = xb + xb_elems;
    dequant_cast_kernel<<<(NVEC / 4) / 256, 256, 0, stream>>>(x, indices, cb,
                                                              scales, xb, wb);
    gemm_bt_kernel<<<(M_DIM / 256) * (N_DIM / 256), 512, 6 * 8192 * 2, stream>>>(
        xb, wb, out);
  } else {
    naive_kernel<<<dim3(N_DIM / 256, M_DIM), 256, 0, stream>>>(x, indices, cb,
                                                               scales, out);
  }
}